// Round 7
// baseline (347.433 us; speedup 1.0000x reference)
//
#include <hip/hip_runtime.h>
#include <math.h>

#define B_   8
#define C_   128
#define E_   8
#define HW_  4096

typedef unsigned short u16;
typedef unsigned int   u32;
typedef __attribute__((ext_vector_type(8))) short bf16x8;
typedef __attribute__((ext_vector_type(4))) float f32x4;

__device__ __forceinline__ u16 f2bf(float f) {
  u32 u = __float_as_uint(f);
  u32 r = (u + 0x7fffu + ((u >> 16) & 1u)) >> 16;
  return (u16)r;
}
__device__ __forceinline__ float bf2f(u16 h) {
  return __uint_as_float(((u32)h) << 16);
}
__device__ __forceinline__ void gld_lds16(const u16* g, u16* l) {
  __builtin_amdgcn_global_load_lds((const __attribute__((address_space(1))) u32*)g,
                                   (__attribute__((address_space(3))) u32*)(void*)l,
                                   16, 0, 0);
}
#define MFMA(a, b, c) __builtin_amdgcn_mfma_f32_16x16x32_bf16(a, b, c, 0, 0, 0)

// ---------------- gates (x0 holds channel SUMS; /4096 is exact pow2 scale) ------
__global__ __launch_bounds__(256) void k_gate(const float* __restrict__ x0,
    const float* __restrict__ g1, const float* __restrict__ g2,
    const float* __restrict__ g3, const float* __restrict__ g4,
    float* __restrict__ wmat, int* __restrict__ needed,
    float* __restrict__ lossp) {
  __shared__ float go[4][8][8];
  int t = threadIdx.x;
  int g = t >> 6, b = (t >> 3) & 7, e = t & 7;
  const float* gp = (g == 0) ? g1 : (g == 1) ? g2 : (g == 2) ? g3 : g4;
  const float* xr = x0 + b * C_;
  float s = 0.f;
  for (int c = 0; c < C_; ++c) s += xr[c] * gp[c * E_ + e];
  s *= (1.f / 4096.f);        // exact: power-of-two scale distributes exactly
  go[g][b][e] = s;
  wmat[t] = 0.f;
  if (t < 64) needed[t] = 0;
  __syncthreads();
  if (t < 32) {
    int gg = t >> 3, bb = t & 7;
    float m = -1e30f;
#pragma unroll
    for (int k = 0; k < 8; ++k) m = fmaxf(m, go[gg][bb][k]);
    float tmp[8]; float sum = 0.f;
#pragma unroll
    for (int k = 0; k < 8; ++k) { tmp[k] = expf(go[gg][bb][k] - m); sum += tmp[k]; }
    float inv = 1.f / sum;
#pragma unroll
    for (int k = 0; k < 8; ++k) { tmp[k] *= inv; go[gg][bb][k] = tmp[k]; }
    float v0 = -1.f; int i0 = 0;
#pragma unroll
    for (int k = 0; k < 8; ++k) if (tmp[k] > v0) { v0 = tmp[k]; i0 = k; }
    float v1 = -1.f; int i1 = 0;
#pragma unroll
    for (int k = 0; k < 8; ++k) if (k != i0 && tmp[k] > v1) { v1 = tmp[k]; i1 = k; }
    float e1 = expf(v1 - v0);
    float w0 = 1.f / (1.f + e1), w1 = e1 / (1.f + e1);
    wmat[(gg * 8 + bb) * 8 + i0] = w0;
    wmat[(gg * 8 + bb) * 8 + i1] = w1;
    needed[i0 * 8 + bb] = 1;
    needed[i1 * 8 + bb] = 1;
  }
  __syncthreads();
  if (t == 0) {
    float total = 0.f;
    for (int gg = 0; gg < 4; ++gg) {
      float us[8]; float mean = 0.f;
      for (int k = 0; k < 8; ++k) {
        float u = 0.f;
        for (int bb = 0; bb < 8; ++bb) u += go[gg][bb][k];
        us[k] = u; mean += u;
      }
      mean *= 0.125f;
      float var = 0.f;
      for (int k = 0; k < 8; ++k) { float d = us[k] - mean; var += d * d; }
      var *= (1.f / 7.f);
      total += var / (mean * mean + 1e-10f);
    }
    *lossp = total;
  }
}

// ---------------- fused prep: X transpose+split (+x0 sums), W pre-swizzle+split --
__global__ __launch_bounds__(256) void k_prep(const float* __restrict__ x,
    const float* __restrict__ Wc, const float* __restrict__ Wp,
    u16* __restrict__ XTh, u16* __restrict__ XTl,
    u16* __restrict__ Wph, u16* __restrict__ Wpl,
    u16* __restrict__ Pph, u16* __restrict__ Ppl, float* __restrict__ x0) {
  __shared__ float T[64 * 129];
  int blk = blockIdx.x;
  if (blk < 512) {
    int y = blk & 63, b = blk >> 6;
    for (int i = threadIdx.x; i < 128 * 64; i += 256) {
      int ci = i >> 6, xc = i & 63;
      T[xc * 129 + ci] = x[((size_t)(b * 128 + ci)) * HW_ + y * 64 + xc];
    }
    __syncthreads();
    if (threadIdx.x < 128) {           // channel partial sums for the gate input
      int ci = threadIdx.x;
      float s = 0.f;
      for (int xc = 0; xc < 64; ++xc) s += T[xc * 129 + ci];
      atomicAdd(&x0[b * 128 + ci], s);
    }
    for (int i = threadIdx.x; i < 64 * 128; i += 256) {
      int xc = i >> 7, ci = i & 127;
      float v = T[xc * 129 + ci];
      u16 h = f2bf(v);
      size_t o = ((size_t)(b * HW_ + y * 64 + xc)) * 128 + ci;
      XTh[o] = h;
      XTl[o] = f2bf(v - bf2f(h));
    }
  } else {
    int gid = (blk - 512) * 256 + threadIdx.x;
    int stride = 1024 * 256;
    const int N1 = 8 * 9 * 2 * 128 * 64;
    for (int g = gid; g < N1; g += stride) {
      int k = g & 63;
      int co = (g >> 6) & 127;
      int ch = (g >> 13) & 1;
      int v = g >> 14;
      int tap = v % 9, e = v / 9;
      int ci = ch * 64 + k;
      float wv = Wc[(((size_t)(e * 128 + co)) * 128 + ci) * 9 + tap];
      u16 h = f2bf(wv), lo = f2bf(wv - bf2f(h));
      int idx = (v * 2 + ch) * 8192 + co * 64 + (k ^ ((co & 7) << 3));
      Wph[idx] = h; Wpl[idx] = lo;
    }
    const int N2 = 8 * 4 * 128 * 32;
    for (int g = gid; g < N2; g += stride) {
      int k = g & 31;
      int co = (g >> 5) & 127;
      int c = (g >> 12) & 3;
      int e = g >> 14;
      int ci = c * 32 + k;
      float wv = Wp[((size_t)(e * 128 + co)) * 128 + ci];
      u16 h = f2bf(wv), lo = f2bf(wv - bf2f(h));
      int idx = (e * 4 + c) * 4096 + co * 32 + (k ^ ((co & 3) << 3));
      Pph[idx] = h; Ppl[idx] = lo;
    }
  }
}

// ---------------- fused expert (round-2 proven structure) + atomic epilogue -----
// grid (32 pos-tiles, b, e), 256 threads = 4 waves (2co x 2n of 64x64).
// K-stage = (tap, ci-chunk 64): A via global_load_lds (pre-swizzled), B reg->LDS
// XOR-swizzled, 96 MFMA/wave between 2 barriers. Squash + 1x1 proj fused.
// Epilogue accumulates wgt*(acc+bias) straight into the 4 gate outputs.
__global__ __launch_bounds__(256, 2) void k_expert(
    const u16* __restrict__ XTh, const u16* __restrict__ XTl,
    const u16* __restrict__ Wph, const u16* __restrict__ Wpl,
    const u16* __restrict__ Pph, const u16* __restrict__ Ppl,
    const float* __restrict__ bcap, const float* __restrict__ bproj,
    const int* __restrict__ needed, const float* __restrict__ wmat,
    float* __restrict__ yout) {
  int e = blockIdx.z, b = blockIdx.y;
  if (!needed[e * 8 + b]) return;
  int tile = blockIdx.x;
  int y0 = tile * 2;

  __shared__ __align__(16) char smem[75264];
  u16* S = (u16*)smem;
  const int Ah = 0, Al = 8192, Bh = 16384, Bl = 24576;   // u16 offsets
  const int Vh = 0, Vl = 16384, Pt = 32768;
  float* snb = (float*)(smem + 73728);
  float* fb  = (float*)(smem + 74752);

  int tid = threadIdx.x;
  int lane = tid & 63, w = tid >> 6;
  int l15 = lane & 15, l4 = lane >> 4;
  int cob = (w >> 1) * 64, nb = (w & 1) * 64;

  f32x4 zero4 = {0.f, 0.f, 0.f, 0.f};
  f32x4 acc[4][4];
#pragma unroll
  for (int i = 0; i < 4; ++i)
#pragma unroll
    for (int j = 0; j < 4; ++j) acc[i][j] = zero4;

  int sn_ = tid >> 1;
  int kh = (tid & 1) * 4;
  int srow = y0 + (sn_ >> 6);
  int scol = sn_ & 63;

  const u16* WphE = Wph + (size_t)e * 9 * 2 * 8192;
  const u16* WplE = Wpl + (size_t)e * 9 * 2 * 8192;

  for (int tap = 0; tap < 9; ++tap) {
    int dy = tap / 3 - 1, dx = tap % 3 - 1;
    int row = srow + dy, col = scol + dx;
    bool val = ((unsigned)row < 64u) && ((unsigned)col < 64u);
    int gidx = val ? ((b * HW_ + row * 64 + col) * 128) : 0;
    for (int ch = 0; ch < 2; ++ch) {
      __syncthreads();   // prior MFMA reads complete before overwrite
      const u16* wsh = WphE + (tap * 2 + ch) * 8192;
      const u16* wsl = WplE + (tap * 2 + ch) * 8192;
#pragma unroll
      for (int q = 0; q < 4; ++q) {
        int off = (w * 4 + q) * 512;
        gld_lds16(wsh + off + lane * 8, S + Ah + off);
        gld_lds16(wsl + off + lane * 8, S + Al + off);
      }
      int ci0 = ch * 64;
#pragma unroll
      for (int i = 0; i < 4; ++i) {
        int kg = kh + i;
        uint4 vh4 = {0u, 0u, 0u, 0u}, vl4 = {0u, 0u, 0u, 0u};
        if (val) {
          vh4 = *(const uint4*)(XTh + gidx + ci0 + kg * 8);
          vl4 = *(const uint4*)(XTl + gidx + ci0 + kg * 8);
        }
        int wa = sn_ * 64 + ((kg * 8) ^ ((sn_ & 7) << 3));
        *(uint4*)(S + Bh + wa) = vh4;
        *(uint4*)(S + Bl + wa) = vl4;
      }
      __syncthreads();
#pragma unroll
      for (int ks = 0; ks < 2; ++ks) {
        bf16x8 fah[4], fal[4], fbh[4], fbl[4];
#pragma unroll
        for (int i = 0; i < 4; ++i) {
          int co = cob + i * 16 + l15;
          int ka = (ks * 32 + l4 * 8) ^ ((co & 7) << 3);
          fah[i] = *(const bf16x8*)(S + Ah + co * 64 + ka);
          fal[i] = *(const bf16x8*)(S + Al + co * 64 + ka);
        }
#pragma unroll
        for (int j = 0; j < 4; ++j) {
          int pn = nb + j * 16 + l15;
          int kb = (ks * 32 + l4 * 8) ^ ((pn & 7) << 3);
          fbh[j] = *(const bf16x8*)(S + Bh + pn * 64 + kb);
          fbl[j] = *(const bf16x8*)(S + Bl + pn * 64 + kb);
        }
#pragma unroll
        for (int i = 0; i < 4; ++i)
#pragma unroll
          for (int j = 0; j < 4; ++j) {
            acc[i][j] = MFMA(fah[i], fbh[j], acc[i][j]);
            acc[i][j] = MFMA(fah[i], fbl[j], acc[i][j]);
            acc[i][j] = MFMA(fal[i], fbh[j], acc[i][j]);
          }
      }
    }
  }

  // caps bias
#pragma unroll
  for (int i = 0; i < 4; ++i)
#pragma unroll
    for (int r = 0; r < 4; ++r) {
      float bc = bcap[e * 128 + cob + i * 16 + l4 * 4 + r];
#pragma unroll
      for (int j = 0; j < 4; ++j) acc[i][j][r] += bc;
    }

  // squash
#pragma unroll
  for (int j = 0; j < 4; ++j) {
    float p = 0.f;
#pragma unroll
    for (int i = 0; i < 4; ++i)
#pragma unroll
      for (int r = 0; r < 4; ++r) p += acc[i][j][r] * acc[i][j][r];
    p += __shfl_xor(p, 16);
    p += __shfl_xor(p, 32);
    if (lane < 16) snb[(w >> 1) * 128 + nb + j * 16 + lane] = p;
  }
  __syncthreads();
  if (tid < 128) {
    float s2 = snb[tid] + snb[128 + tid];
    fb[tid] = s2 / ((1.f + s2) * (sqrtf(s2) + 1e-8f));
  }
  __syncthreads();

  // v = u*f -> LDS bf16 hi/lo [128 pos][128 ci], swizzled
#pragma unroll
  for (int j = 0; j < 4; ++j) {
    int pn = nb + j * 16 + l15;
    float fj = fb[pn];
#pragma unroll
    for (int i = 0; i < 4; ++i) {
      int co0v = cob + i * 16 + l4 * 4;
      float v0 = acc[i][j][0] * fj, v1 = acc[i][j][1] * fj;
      float v2 = acc[i][j][2] * fj, v3 = acc[i][j][3] * fj;
      u16 h0 = f2bf(v0), h1 = f2bf(v1), h2 = f2bf(v2), h3 = f2bf(v3);
      uint2 hp; hp.x = (u32)h0 | ((u32)h1 << 16); hp.y = (u32)h2 | ((u32)h3 << 16);
      u16 q0 = f2bf(v0 - bf2f(h0)), q1 = f2bf(v1 - bf2f(h1));
      u16 q2 = f2bf(v2 - bf2f(h2)), q3 = f2bf(v3 - bf2f(h3));
      uint2 lp; lp.x = (u32)q0 | ((u32)q1 << 16); lp.y = (u32)q2 | ((u32)q3 << 16);
      int ad = pn * 128 + (co0v ^ ((pn & 7) << 3));
      *(uint2*)(S + Vh + ad) = hp;
      *(uint2*)(S + Vl + ad) = lp;
    }
  }
  __syncthreads();

  // 1x1 proj
#pragma unroll
  for (int i = 0; i < 4; ++i)
#pragma unroll
    for (int j = 0; j < 4; ++j) acc[i][j] = zero4;

  for (int sp = 0; sp < 2; ++sp) {
    const u16* Psrc = sp ? Ppl : Pph;
    for (int c = 0; c < 4; ++c) {
      __syncthreads();
      const u16* ps = Psrc + (size_t)(e * 4 + c) * 4096;
#pragma unroll
      for (int q = 0; q < 2; ++q) {
        int off = (w * 2 + q) * 512;
        gld_lds16(ps + off + lane * 8, S + Pt + off);
      }
      __syncthreads();
      bf16x8 af[4], bvh[4], bvl[4];
#pragma unroll
      for (int i = 0; i < 4; ++i) {
        int co = cob + i * 16 + l15;
        int ka = (l4 * 8) ^ ((co & 3) << 3);
        af[i] = *(const bf16x8*)(S + Pt + co * 32 + ka);
      }
#pragma unroll
      for (int j = 0; j < 4; ++j) {
        int pn = nb + j * 16 + l15;
        int kb = (c * 32 + l4 * 8) ^ ((pn & 7) << 3);
        bvh[j] = *(const bf16x8*)(S + Vh + pn * 128 + kb);
        bvl[j] = *(const bf16x8*)(S + Vl + pn * 128 + kb);
      }
      if (sp == 0) {
#pragma unroll
        for (int i = 0; i < 4; ++i)
#pragma unroll
          for (int j = 0; j < 4; ++j) {
            acc[i][j] = MFMA(af[i], bvh[j], acc[i][j]);
            acc[i][j] = MFMA(af[i], bvl[j], acc[i][j]);
          }
      } else {
#pragma unroll
        for (int i = 0; i < 4; ++i)
#pragma unroll
          for (int j = 0; j < 4; ++j)
            acc[i][j] = MFMA(af[i], bvh[j], acc[i][j]);
      }
    }
  }

  // epilogue: accumulate wgt*(acc + bias) directly into gate outputs
  int posbase = tile * 128;
  float wg0 = wmat[(0 * 8 + b) * 8 + e];
  float wg1 = wmat[(1 * 8 + b) * 8 + e];
  float wg2 = wmat[(2 * 8 + b) * 8 + e];
  float wg3 = wmat[(3 * 8 + b) * 8 + e];
  float* o0 = yout + (size_t)(0 * 8 + b) * (C_ * HW_);
  float* o1 = yout + (size_t)(1 * 8 + b) * (C_ * HW_);
  float* o2 = yout + (size_t)(2 * 8 + b) * (C_ * HW_);
  float* o3 = yout + (size_t)(3 * 8 + b) * (C_ * HW_);
#pragma unroll
  for (int i = 0; i < 4; ++i)
#pragma unroll
    for (int r = 0; r < 4; ++r) {
      int co = cob + i * 16 + l4 * 4 + r;
      float bp = bproj[e * 128 + co];
      size_t rowo = (size_t)co * HW_ + posbase;
#pragma unroll
      for (int j = 0; j < 4; ++j) {
        int p = nb + j * 16 + l15;
        float v = acc[i][j][r] + bp;
        if (wg0 != 0.f) atomicAdd(o0 + rowo + p, wg0 * v);
        if (wg1 != 0.f) atomicAdd(o1 + rowo + p, wg1 * v);
        if (wg2 != 0.f) atomicAdd(o2 + rowo + p, wg2 * v);
        if (wg3 != 0.f) atomicAdd(o3 + rowo + p, wg3 * v);
      }
    }
}

extern "C" void kernel_launch(void* const* d_in, const int* in_sizes, int n_in,
                              void* d_out, int out_size, void* d_ws, size_t ws_size,
                              hipStream_t stream) {
  const float* x  = (const float*)d_in[0];
  const float* g1 = (const float*)d_in[1];
  const float* g2 = (const float*)d_in[2];
  const float* g3 = (const float*)d_in[3];
  const float* g4 = (const float*)d_in[4];
  const float* Wc = (const float*)d_in[5];
  const float* bc = (const float*)d_in[6];
  const float* Wp = (const float*)d_in[7];
  const float* bp = (const float*)d_in[8];
  float* out = (float*)d_out;

  const size_t XTU  = (size_t)B_ * HW_ * C_;        // 4.19M u16 each
  const size_t WSU  = (size_t)8 * 9 * 2 * 8192;
  const size_t PSU  = (size_t)8 * 4 * 4096;

  char* p = (char*)d_ws;
  u16* XTh = (u16*)p; p += XTU * 2;
  u16* XTl = (u16*)p; p += XTU * 2;
  u16* Wph = (u16*)p; p += WSU * 2;
  u16* Wpl = (u16*)p; p += WSU * 2;
  u16* Pph = (u16*)p; p += PSU * 2;
  u16* Ppl = (u16*)p; p += PSU * 2;
  float* x0   = (float*)p; p += 1024 * 4;
  float* wmat = (float*)p; p += 256 * 4;
  int*   needed = (int*)p; p += 64 * 4;

  // zero the 4 gate outputs (atomic accumulation targets) and x0 partials
  hipMemsetAsync(out, 0, (size_t)4 * B_ * C_ * HW_ * 4, stream);
  hipMemsetAsync(x0, 0, 1024 * 4, stream);

  k_prep<<<dim3(1536), dim3(256), 0, stream>>>(x, Wc, Wp, XTh, XTl, Wph, Wpl,
                                               Pph, Ppl, x0);
  k_gate<<<dim3(1), dim3(256), 0, stream>>>(x0, g1, g2, g3, g4, wmat, needed,
                                            out + (size_t)4 * B_ * C_ * HW_);
  k_expert<<<dim3(32, B_, E_), dim3(256), 0, stream>>>(
      XTh, XTl, Wph, Wpl, Pph, Ppl, bc, bp, needed, wmat, out);
}

// Round 8
// 289.991 us; speedup vs baseline: 1.1981x; 1.1981x over previous
//
#include <hip/hip_runtime.h>
#include <math.h>

#define B_   8
#define C_   128
#define E_   8
#define HW_  4096

typedef unsigned short u16;
typedef unsigned int   u32;
typedef __attribute__((ext_vector_type(8))) short bf16x8;
typedef __attribute__((ext_vector_type(4))) float f32x4;

__device__ __forceinline__ u16 f2bf(float f) {
  u32 u = __float_as_uint(f);
  u32 r = (u + 0x7fffu + ((u >> 16) & 1u)) >> 16;
  return (u16)r;
}
__device__ __forceinline__ float bf2f(u16 h) {
  return __uint_as_float(((u32)h) << 16);
}
__device__ __forceinline__ void gld_lds16(const u16* g, u16* l) {
  __builtin_amdgcn_global_load_lds((const __attribute__((address_space(1))) u32*)g,
                                   (__attribute__((address_space(3))) u32*)(void*)l,
                                   16, 0, 0);
}
#define MFMA(a, b, c) __builtin_amdgcn_mfma_f32_16x16x32_bf16(a, b, c, 0, 0, 0)

// ---------------- gates (x0 = channel sums; /4096 exact pow2) -------------------
__global__ __launch_bounds__(256) void k_gate(const float* __restrict__ x0,
    const float* __restrict__ g1, const float* __restrict__ g2,
    const float* __restrict__ g3, const float* __restrict__ g4,
    float* __restrict__ wmat, int* __restrict__ needed,
    float* __restrict__ lossp) {
  __shared__ float go[4][8][8];
  int t = threadIdx.x;
  int g = t >> 6, b = (t >> 3) & 7, e = t & 7;
  const float* gp = (g == 0) ? g1 : (g == 1) ? g2 : (g == 2) ? g3 : g4;
  const float* xr = x0 + b * C_;
  float s = 0.f;
  for (int c = 0; c < C_; ++c) s += xr[c] * gp[c * E_ + e];
  s *= (1.f / 4096.f);
  go[g][b][e] = s;
  wmat[t] = 0.f;
  if (t < 64) needed[t] = 0;
  __syncthreads();
  if (t < 32) {
    int gg = t >> 3, bb = t & 7;
    float m = -1e30f;
#pragma unroll
    for (int k = 0; k < 8; ++k) m = fmaxf(m, go[gg][bb][k]);
    float tmp[8]; float sum = 0.f;
#pragma unroll
    for (int k = 0; k < 8; ++k) { tmp[k] = expf(go[gg][bb][k] - m); sum += tmp[k]; }
    float inv = 1.f / sum;
#pragma unroll
    for (int k = 0; k < 8; ++k) { tmp[k] *= inv; go[gg][bb][k] = tmp[k]; }
    float v0 = -1.f; int i0 = 0;
#pragma unroll
    for (int k = 0; k < 8; ++k) if (tmp[k] > v0) { v0 = tmp[k]; i0 = k; }
    float v1 = -1.f; int i1 = 0;
#pragma unroll
    for (int k = 0; k < 8; ++k) if (k != i0 && tmp[k] > v1) { v1 = tmp[k]; i1 = k; }
    float e1 = expf(v1 - v0);
    float w0 = 1.f / (1.f + e1), w1 = e1 / (1.f + e1);
    wmat[(gg * 8 + bb) * 8 + i0] = w0;
    wmat[(gg * 8 + bb) * 8 + i1] = w1;
    needed[i0 * 8 + bb] = 1;
    needed[i1 * 8 + bb] = 1;
  }
  __syncthreads();
  if (t == 0) {
    float total = 0.f;
    for (int gg = 0; gg < 4; ++gg) {
      float us[8]; float mean = 0.f;
      for (int k = 0; k < 8; ++k) {
        float u = 0.f;
        for (int bb = 0; bb < 8; ++bb) u += go[gg][bb][k];
        us[k] = u; mean += u;
      }
      mean *= 0.125f;
      float var = 0.f;
      for (int k = 0; k < 8; ++k) { float d = us[k] - mean; var += d * d; }
      var *= (1.f / 7.f);
      total += var / (mean * mean + 1e-10f);
    }
    *lossp = total;
  }
}

// ---------------- prep: X transpose+split (+x0), slot-interleaved W tables ------
// At[e][tap][ch4][co128][sl8][8]: slot s = sl^(co&7); s<4 -> hi of ci=ch*32+(s&3)*8+t,
// s>=4 -> lo residual. Pt_t[e][chp4][co128][sl8][8] same scheme.
__global__ __launch_bounds__(256) void k_prep(const float* __restrict__ x,
    const float* __restrict__ Wc, const float* __restrict__ Wp,
    u16* __restrict__ XTh, u16* __restrict__ XTl,
    u16* __restrict__ At, u16* __restrict__ Pt_t,
    float* __restrict__ x0, u16* __restrict__ zp) {
  __shared__ float T[64 * 129];
  int blk = blockIdx.x;
  if (blk < 512) {
    int y = blk & 63, b = blk >> 6;
    for (int i = threadIdx.x; i < 128 * 64; i += 256) {
      int ci = i >> 6, xc = i & 63;
      T[xc * 129 + ci] = x[((size_t)(b * 128 + ci)) * HW_ + y * 64 + xc];
    }
    __syncthreads();
    if (threadIdx.x < 128) {
      int ci = threadIdx.x;
      float s = 0.f;
      for (int xc = 0; xc < 64; ++xc) s += T[xc * 129 + ci];
      atomicAdd(&x0[b * 128 + ci], s);
    }
    for (int i = threadIdx.x; i < 64 * 128; i += 256) {
      int xc = i >> 7, ci = i & 127;
      float v = T[xc * 129 + ci];
      u16 h = f2bf(v);
      size_t o = ((size_t)(b * HW_ + y * 64 + xc)) * 128 + ci;
      XTh[o] = h;
      XTl[o] = f2bf(v - bf2f(h));
    }
  } else {
    if (blk == 512 && threadIdx.x < 64) zp[threadIdx.x] = 0;
    int gid = (blk - 512) * 256 + threadIdx.x;
    int stride = 1024 * 256;
    const int N1 = 8 * 9 * 4 * 128 * 64;     // 2359296
    for (int g = gid; g < N1; g += stride) {
      int t = g & 7;
      int sl = (g >> 3) & 7;
      int co = (g >> 6) & 127;
      int ch = (g >> 13) & 3;
      int v = g >> 15;                        // e*9+tap
      int tap = v % 9, e = v / 9;
      int s = sl ^ (co & 7);
      int ci = ch * 32 + (s & 3) * 8 + t;
      float wv = Wc[(((size_t)(e * 128 + co)) * 128 + ci) * 9 + tap];
      u16 h = f2bf(wv);
      At[g] = (s < 4) ? h : f2bf(wv - bf2f(h));
    }
    const int N2 = 8 * 4 * 128 * 64;          // 262144
    for (int g = gid; g < N2; g += stride) {
      int t = g & 7;
      int sl = (g >> 3) & 7;
      int co = (g >> 6) & 127;
      int chp = (g >> 13) & 3;
      int e = g >> 15;
      int s = sl ^ (co & 7);
      int ci = chp * 32 + (s & 3) * 8 + t;
      float wv = Wp[((size_t)(e * 128 + co)) * 128 + ci];
      u16 h = f2bf(wv);
      Pt_t[g] = (s < 4) ? h : f2bf(wv - bf2f(h));
    }
  }
}

// ---------------- fused expert: dbuf gld_lds pipeline, counted vmcnt, 2 blk/CU --
// grid (32 tiles, 8 b, 8 e), 256 thr = 4 waves (2co x 2n, 64x64 each).
// Conv: 36 stages (9 taps x 4 ci-chunks of 32). LDS 80 KB: dbuf 2x32KB -> V 64KB
// alias + Pt 16KB. Per stage/wave: 8 gld_lds for s+1, vmcnt(8), barrier, 48 MFMA.
__global__ __launch_bounds__(256, 2) void k_expert(
    const u16* __restrict__ XTh, const u16* __restrict__ XTl,
    const u16* __restrict__ At, const u16* __restrict__ Pt_t,
    const float* __restrict__ bcap, const float* __restrict__ bproj,
    const int* __restrict__ needed, const u16* __restrict__ zp,
    float* __restrict__ expb) {
  int e = blockIdx.z, b = blockIdx.y;
  if (!needed[e * 8 + b]) return;
  int tile = blockIdx.x;

  __shared__ __align__(16) char smem[81920];
  u16* S = (u16*)smem;
  float* snb = (float*)(smem + 65536);   // [2][128] (pre-proj only, aliases Pt)
  float* fb  = (float*)(smem + 66560);   // [128]

  int tid = threadIdx.x;
  int lane = tid & 63, w = tid >> 6;
  int l15 = lane & 15, l4 = lane >> 4;
  int cob = (w >> 1) * 64, nb = (w & 1) * 64;

  f32x4 zero4 = {0.f, 0.f, 0.f, 0.f};
  f32x4 acc[4][4];
#pragma unroll
  for (int i = 0; i < 4; ++i)
#pragma unroll
    for (int j = 0; j < 4; ++j) acc[i][j] = zero4;

  auto STAGE = [&](int st, int buf) {
    int tap = st >> 2, ch = st & 3;
    const u16* Ab = At + (size_t)((e * 9 + tap) * 4 + ch) * 8192;
#pragma unroll
    for (int q = 0; q < 4; ++q) {
      int m = w * 4 + q;
      gld_lds16(Ab + m * 512 + lane * 8, S + buf + m * 512);
    }
    int dy = tap / 3 - 1, dx = tap % 3 - 1;
#pragma unroll
    for (int q = 0; q < 4; ++q) {
      int m = w * 4 + q;
      int pn = m * 8 + (lane >> 3);
      int sv = (lane & 7) ^ (pn & 7);
      int gy = tile * 2 + (pn >> 6) + dy;
      int gx = (pn & 63) + dx;
      bool val = ((unsigned)gy < 64u) && ((unsigned)gx < 64u);
      int go_ = ((b << 12) + gy * 64 + gx) * 128 + ch * 32 + (sv & 3) * 8;
      const u16* src = val ? ((sv < 4 ? XTh : XTl) + go_) : zp;
      gld_lds16(src, S + buf + 8192 + m * 512);
    }
  };

  STAGE(0, 0);
  for (int s = 0; s < 36; ++s) {
    int cur = (s & 1) * 16384;
    if (s < 35) {
      STAGE(s + 1, ((s + 1) & 1) * 16384);
      asm volatile("s_waitcnt vmcnt(8)" ::: "memory");
    } else {
      asm volatile("s_waitcnt vmcnt(0)" ::: "memory");
    }
    __builtin_amdgcn_s_barrier();
    __builtin_amdgcn_sched_barrier(0);
    bf16x8 fah[4], fal[4], fbh[4], fbl[4];
#pragma unroll
    for (int i = 0; i < 4; ++i) {
      int co = cob + i * 16 + l15;
      int sa = (l4 ^ (co & 7)) * 8;
      fah[i] = *(const bf16x8*)(S + cur + co * 64 + sa);
      fal[i] = *(const bf16x8*)(S + cur + co * 64 + (sa ^ 32));
    }
#pragma unroll
    for (int j = 0; j < 4; ++j) {
      int pn = nb + j * 16 + l15;
      int sb = (l4 ^ (pn & 7)) * 8;
      fbh[j] = *(const bf16x8*)(S + cur + 8192 + pn * 64 + sb);
      fbl[j] = *(const bf16x8*)(S + cur + 8192 + pn * 64 + (sb ^ 32));
    }
    __builtin_amdgcn_s_setprio(1);
#pragma unroll
    for (int i = 0; i < 4; ++i)
#pragma unroll
      for (int j = 0; j < 4; ++j) {
        acc[i][j] = MFMA(fah[i], fbh[j], acc[i][j]);
        acc[i][j] = MFMA(fah[i], fbl[j], acc[i][j]);
        acc[i][j] = MFMA(fal[i], fbh[j], acc[i][j]);
      }
    __builtin_amdgcn_s_setprio(0);
    __builtin_amdgcn_sched_barrier(0);
    __builtin_amdgcn_s_barrier();
  }

  // caps bias
#pragma unroll
  for (int i = 0; i < 4; ++i)
#pragma unroll
    for (int r = 0; r < 4; ++r) {
      float bc = bcap[e * 128 + cob + i * 16 + l4 * 4 + r];
#pragma unroll
      for (int j = 0; j < 4; ++j) acc[i][j][r] += bc;
    }

  // squash
#pragma unroll
  for (int j = 0; j < 4; ++j) {
    float p = 0.f;
#pragma unroll
    for (int i = 0; i < 4; ++i)
#pragma unroll
      for (int r = 0; r < 4; ++r) p += acc[i][j][r] * acc[i][j][r];
    p += __shfl_xor(p, 16);
    p += __shfl_xor(p, 32);
    if (lane < 16) snb[(w >> 1) * 128 + nb + j * 16 + lane] = p;
  }
  __syncthreads();
  if (tid < 128) {
    float s2 = snb[tid] + snb[128 + tid];
    fb[tid] = s2 / ((1.f + s2) * (sqrtf(s2) + 1e-8f));
  }
  __syncthreads();

  // v = u*f -> V in slot-interleaved layout [chp4][pos128][sl8][8] @ S+0 (64 KB)
#pragma unroll
  for (int j = 0; j < 4; ++j) {
    int pn = nb + j * 16 + l15;
    float fj = fb[pn];
    int prow = pn * 64;
#pragma unroll
    for (int i = 0; i < 4; ++i) {
      int cobase = cob + i * 16;
      float v0 = acc[i][j][0] * fj, v1 = acc[i][j][1] * fj;
      float v2 = acc[i][j][2] * fj, v3 = acc[i][j][3] * fj;
      u16 h0 = f2bf(v0), h1 = f2bf(v1), h2 = f2bf(v2), h3 = f2bf(v3);
      uint2 hp; hp.x = (u32)h0 | ((u32)h1 << 16); hp.y = (u32)h2 | ((u32)h3 << 16);
      u16 q0 = f2bf(v0 - bf2f(h0)), q1 = f2bf(v1 - bf2f(h1));
      u16 q2 = f2bf(v2 - bf2f(h2)), q3 = f2bf(v3 - bf2f(h3));
      uint2 lp; lp.x = (u32)q0 | ((u32)q1 << 16); lp.y = (u32)q2 | ((u32)q3 << 16);
      int chp = cobase >> 5;
      int kg = ((cobase >> 3) + (l4 >> 1)) & 3;
      int ad = chp * 8192 + prow + (kg ^ (pn & 7)) * 8 + (l4 & 1) * 4;
      *(uint2*)(S + ad) = hp;
      *(uint2*)(S + (ad ^ 32)) = lp;
    }
  }
  __syncthreads();

  // 1x1 proj: 4 chp stages, P tile 16 KB @ u16 32768
#pragma unroll
  for (int i = 0; i < 4; ++i)
#pragma unroll
    for (int j = 0; j < 4; ++j) acc[i][j] = zero4;

  for (int chp = 0; chp < 4; ++chp) {
    const u16* Pb = Pt_t + (size_t)(e * 4 + chp) * 8192;
#pragma unroll
    for (int q = 0; q < 4; ++q) {
      int m = w * 4 + q;
      gld_lds16(Pb + m * 512 + lane * 8, S + 32768 + m * 512);
    }
    __syncthreads();
    bf16x8 afh[4], afl[4], bvh[4], bvl[4];
#pragma unroll
    for (int i = 0; i < 4; ++i) {
      int co = cob + i * 16 + l15;
      int sa = (l4 ^ (co & 7)) * 8;
      afh[i] = *(const bf16x8*)(S + 32768 + co * 64 + sa);
      afl[i] = *(const bf16x8*)(S + 32768 + co * 64 + (sa ^ 32));
    }
#pragma unroll
    for (int j = 0; j < 4; ++j) {
      int pn = nb + j * 16 + l15;
      int sb = (l4 ^ (pn & 7)) * 8;
      bvh[j] = *(const bf16x8*)(S + chp * 8192 + pn * 64 + sb);
      bvl[j] = *(const bf16x8*)(S + chp * 8192 + pn * 64 + (sb ^ 32));
    }
    __builtin_amdgcn_s_setprio(1);
#pragma unroll
    for (int i = 0; i < 4; ++i)
#pragma unroll
      for (int j = 0; j < 4; ++j) {
        acc[i][j] = MFMA(afh[i], bvh[j], acc[i][j]);
        acc[i][j] = MFMA(afh[i], bvl[j], acc[i][j]);
        acc[i][j] = MFMA(afl[i], bvh[j], acc[i][j]);
      }
    __builtin_amdgcn_s_setprio(0);
    __syncthreads();
  }

  // epilogue: plain expb stores (atomics measured 120us slower — round 7)
  int posbase = tile * 128;
  float* ob = expb + ((size_t)((e * 8 + b) * 128)) * HW_;
#pragma unroll
  for (int i = 0; i < 4; ++i)
#pragma unroll
    for (int r = 0; r < 4; ++r) {
      int co = cob + i * 16 + l4 * 4 + r;
      float bp = bproj[e * 128 + co];
      size_t rowo = (size_t)co * HW_ + posbase;
#pragma unroll
      for (int j = 0; j < 4; ++j)
        ob[rowo + nb + j * 16 + l15] = acc[i][j][r] + bp;
    }
}

// ---------------- combine: per-b union of experts, one pass over all 4 gates ----
__global__ __launch_bounds__(256) void k_combine(const float* __restrict__ expb,
    const float* __restrict__ wmat, float* __restrict__ yout) {
  int b = blockIdx.y;
  float wg[4][8];
#pragma unroll
  for (int g = 0; g < 4; ++g)
#pragma unroll
    for (int e = 0; e < 8; ++e) wg[g][e] = wmat[(g * 8 + b) * 8 + e];
  const int NV = C_ * HW_ / 4;
  for (int i = blockIdx.x * 256 + threadIdx.x; i < NV; i += gridDim.x * 256) {
    float4 a0 = {0.f, 0.f, 0.f, 0.f}, a1 = a0, a2 = a0, a3 = a0;
#pragma unroll
    for (int e = 0; e < 8; ++e) {
      float w0 = wg[0][e], w1 = wg[1][e], w2 = wg[2][e], w3 = wg[3][e];
      if (w0 == 0.f && w1 == 0.f && w2 == 0.f && w3 == 0.f) continue;
      float4 v = ((const float4*)(expb + (size_t)(e * 8 + b) * (C_ * HW_)))[i];
      a0.x += w0 * v.x; a0.y += w0 * v.y; a0.z += w0 * v.z; a0.w += w0 * v.w;
      a1.x += w1 * v.x; a1.y += w1 * v.y; a1.z += w1 * v.z; a1.w += w1 * v.w;
      a2.x += w2 * v.x; a2.y += w2 * v.y; a2.z += w2 * v.z; a2.w += w2 * v.w;
      a3.x += w3 * v.x; a3.y += w3 * v.y; a3.z += w3 * v.z; a3.w += w3 * v.w;
    }
    ((float4*)(yout + (size_t)(0 * 8 + b) * (C_ * HW_)))[i] = a0;
    ((float4*)(yout + (size_t)(1 * 8 + b) * (C_ * HW_)))[i] = a1;
    ((float4*)(yout + (size_t)(2 * 8 + b) * (C_ * HW_)))[i] = a2;
    ((float4*)(yout + (size_t)(3 * 8 + b) * (C_ * HW_)))[i] = a3;
  }
}

extern "C" void kernel_launch(void* const* d_in, const int* in_sizes, int n_in,
                              void* d_out, int out_size, void* d_ws, size_t ws_size,
                              hipStream_t stream) {
  const float* x  = (const float*)d_in[0];
  const float* g1 = (const float*)d_in[1];
  const float* g2 = (const float*)d_in[2];
  const float* g3 = (const float*)d_in[3];
  const float* g4 = (const float*)d_in[4];
  const float* Wc = (const float*)d_in[5];
  const float* bc = (const float*)d_in[6];
  const float* Wp = (const float*)d_in[7];
  const float* bp = (const float*)d_in[8];
  float* out = (float*)d_out;

  const size_t EXPF = (size_t)E_ * B_ * C_ * HW_;   // 134 MB
  const size_t XTU  = (size_t)B_ * HW_ * C_;        // 8.4 MB each
  const size_t ATU  = (size_t)8 * 9 * 4 * 128 * 64; // 2359296 u16
  const size_t PTU  = (size_t)8 * 4 * 128 * 64;     // 262144 u16

  char* p = (char*)d_ws;
  float* expb = (float*)p; p += EXPF * 4;
  u16* XTh  = (u16*)p; p += XTU * 2;
  u16* XTl  = (u16*)p; p += XTU * 2;
  u16* At   = (u16*)p; p += ATU * 2;
  u16* Pt_t = (u16*)p; p += PTU * 2;
  float* x0   = (float*)p; p += 1024 * 4;
  float* wmat = (float*)p; p += 256 * 4;
  int*   needed = (int*)p; p += 64 * 4;
  u16*   zp = (u16*)p;     p += 128;

  hipMemsetAsync(x0, 0, 1024 * 4, stream);

  k_prep<<<dim3(1536), dim3(256), 0, stream>>>(x, Wc, Wp, XTh, XTl, At, Pt_t,
                                               x0, zp);
  k_gate<<<dim3(1), dim3(256), 0, stream>>>(x0, g1, g2, g3, g4, wmat, needed,
                                            out + (size_t)4 * B_ * C_ * HW_);
  k_expert<<<dim3(32, B_, E_), dim3(256), 0, stream>>>(
      XTh, XTl, At, Pt_t, bc, bp, needed, zp, expb);
  k_combine<<<dim3(128, B_), dim3(256), 0, stream>>>(expb, wmat, out);
}